// Round 21
// baseline (66.932 us; speedup 1.0000x reference)
//
#include <hip/hip_runtime.h>
#include <hip/hip_bf16.h>

#define BATCH  512
#define IN_F   4096
#define OUT_F  4096

typedef __attribute__((ext_vector_type(8))) short bf16x8;   // 8 bf16 = 4 VGPR (MFMA A/B frag)
typedef __attribute__((ext_vector_type(4))) float f32x4;    // MFMA C/D frag

// bf16 round-to-nearest-even bits from fp32
__device__ __forceinline__ unsigned bf16_bits(float f) {
    unsigned u = __float_as_uint(f);
    return (u + 0x7FFFu + ((u >> 16) & 1u)) >> 16;
}
__device__ __forceinline__ float bf16_val(unsigned bits16) {
    return __uint_as_float(bits16 << 16);
}

// ---------------- 1) fused scatter (bf16 CAS-add into zeroed W)  +  x fp32->bf16 ----------------
// The two jobs are independent; fusing them overlaps the convert's streaming traffic
// with the scatter's latency-bound random RMWs. W must be pre-zeroed (hipMemsetAsync).
__device__ __forceinline__ void add_bf16(unsigned* __restrict__ Wb32, int r, int c, float val) {
    unsigned* addr = &Wb32[((size_t)r * IN_F + c) >> 1];
    const bool hi = c & 1;
    unsigned old = *addr, assumed;
    do {
        assumed = old;
        unsigned cur = hi ? (assumed >> 16) : (assumed & 0xFFFFu);
        unsigned nb  = bf16_bits(bf16_val(cur) + val);
        unsigned next = hi ? ((nb << 16) | (assumed & 0xFFFFu))
                           : ((assumed & 0xFFFF0000u) | nb);
        old = atomicCAS(addr, assumed, next);
    } while (old != assumed);
}

#define NC4 (BATCH * IN_F / 16)          // 131072 convert threads (4 float4 each)

__global__ void scatter_convert_kernel(const int* __restrict__ rows,
                                       const int* __restrict__ cols,
                                       const float* __restrict__ w,
                                       int nnz,
                                       unsigned* __restrict__ Wb32,
                                       const float* __restrict__ x,
                                       __hip_bfloat16* __restrict__ xb) {
    const int NS = (nnz + 3) / 4;        // scatter threads (4 entries each)
    int gtid = blockIdx.x * blockDim.x + threadIdx.x;
    if (gtid < NS) {
        int i4 = gtid * 4;
        if (i4 + 4 <= nnz) {
            int4   r  = ((const int4*)rows)[gtid];
            int4   c  = ((const int4*)cols)[gtid];
            float4 wv = ((const float4*)w)[gtid];
            add_bf16(Wb32, r.x, c.x, wv.x);
            add_bf16(Wb32, r.y, c.y, wv.y);
            add_bf16(Wb32, r.z, c.z, wv.z);
            add_bf16(Wb32, r.w, c.w, wv.w);
        } else {
            for (int j = i4; j < nnz; ++j)
                add_bf16(Wb32, rows[j], cols[j], w[j]);
        }
    } else {
        int i = gtid - NS;               // 0 .. NC4-1 : convert 4 float4 (strided for coalescing)
        if (i < NC4) {
#pragma unroll
            for (int j = 0; j < 4; ++j) {
                int u = i + j * NC4;     // float4 index, lane-consecutive within each pass
                float4 v = ((const float4*)x)[u];
                unsigned lo = bf16_bits(v.x) | (bf16_bits(v.y) << 16);
                unsigned hi = bf16_bits(v.z) | (bf16_bits(v.w) << 16);
                ((uint2*)xb)[u] = make_uint2(lo, hi);
            }
        }
    }
}

// ---------------- 2) GEMM: part[ksp] = x_bf16 @ W^T (slice) -- R14/R20-byte-exact ----------------
// 256^2 tile, BK=64, 8 waves 2Mx4N, counted vmcnt(8), pre-swizzled row-major LDS
// (coalesced staging + 0 bank conflicts, measured). XCD-paired mapping; bf16-packed
// partial streams (no atomics).
#define BM  256
#define BN  256
#define BKT 64
#define KSPLIT 8
#define KH   (IN_F / KSPLIT)            // 512
#define NKTH (KH / BKT)                 // 8
#define NWG  ((BATCH / BM) * (OUT_F / BN) * KSPLIT)   // 256

__global__ __launch_bounds__(512, 1) void gemm_part_kernel(
    const __hip_bfloat16* __restrict__ xb,   // (512, 4096) row-major
    const __hip_bfloat16* __restrict__ Wb,   // (4096, 4096) = (N, K) row-major
    unsigned* __restrict__ parts) {          // KSPLIT x (256, 4096) uint (2 bf16 rows each)

    __shared__ __align__(16) __hip_bfloat16 As[2][BM][BKT];   // 64 KB
    __shared__ __align__(16) __hip_bfloat16 Bs[2][BN][BKT];   // 64 KB

    // XCD-paired decomposition (xcd heuristic: bid % 8)
    const int xcd = blockIdx.x & 7;
    const int r   = blockIdx.x >> 3;          // 0..31
    const int bn0 = (2 * xcd + (r & 1)) * BN; // n tile 0..15
    const int bm0 = ((r >> 1) & 1) * BM;      // m tile 0..1
    const int ksp = r >> 2;                   // 0..7
    const size_t k0 = (size_t)ksp * KH;

    const int t  = threadIdx.x;               // 0..511
    const int l  = t & 63;
    const int w  = t >> 6;                    // wave 0..7
    const int wr = w >> 2;                    // M-half 0..1 (128 rows)
    const int wc = w & 3;                     // N-quarter 0..3 (64 cols)
    const int lr = l & 15;                    // frag lane
    const int lg = l >> 4;                    // k-group 0..3

    f32x4 acc[8][4] = {};

#define STAGE(p, kt) do {                                                                         \
    _Pragma("unroll")                                                                             \
    for (int j = 0; j < 4; ++j) {                                                                 \
        int q = t + j * 512; int row = q >> 3; int kcg = (q & 7) ^ (row & 7);                     \
        __builtin_amdgcn_global_load_lds(                                                         \
            (const unsigned*)(xb + (size_t)(bm0 + row) * IN_F + k0 + (kt) * BKT + kcg * 8),       \
            (unsigned*)((__hip_bfloat16*)As[p] + q * 8), 16, 0, 0);                               \
    }                                                                                             \
    _Pragma("unroll")                                                                             \
    for (int j = 0; j < 4; ++j) {                                                                 \
        int q = t + j * 512; int row = q >> 3; int kcg = (q & 7) ^ (row & 7);                     \
        __builtin_amdgcn_global_load_lds(                                                         \
            (const unsigned*)(Wb + (size_t)(bn0 + row) * IN_F + k0 + (kt) * BKT + kcg * 8),       \
            (unsigned*)((__hip_bfloat16*)Bs[p] + q * 8), 16, 0, 0);                               \
    }                                                                                             \
} while (0)

    const int rowA0 = wr * 128 + lr;          // +16i ; (row&7) == (lr&7) for all i
    const int rowB0 = wc * 64 + lr;
    const int xA = lr & 7;
    const int xB = lr & 7;

    STAGE(0, 0);
    for (int kt = 0; kt < NKTH; ++kt) {
        const int p = kt & 1;
        if (kt + 1 < NKTH) {
            STAGE(p ^ 1, kt + 1);                              // 8 more loads in flight
            asm volatile("s_waitcnt vmcnt(8)" ::: "memory");   // tile kt's 8 landed
        } else {
            asm volatile("s_waitcnt vmcnt(0)" ::: "memory");   // final tile: full drain
        }
        __builtin_amdgcn_s_barrier();                          // all waves: tile kt ready

#pragma unroll
        for (int ks = 0; ks < 2; ++ks) {
            const int kc = ks * 4 + lg;
            bf16x8 a[8], b[4];
#pragma unroll
            for (int i = 0; i < 8; ++i)
                a[i] = *(const bf16x8*)&As[p][rowA0 + 16 * i][(kc ^ xA) * 8];
#pragma unroll
            for (int i = 0; i < 4; ++i)
                b[i] = *(const bf16x8*)&Bs[p][rowB0 + 16 * i][(kc ^ xB) * 8];
#pragma unroll
            for (int i = 0; i < 8; ++i)
#pragma unroll
                for (int j = 0; j < 4; ++j)
                    acc[i][j] = __builtin_amdgcn_mfma_f32_16x16x32_bf16(a[i], b[j], acc[i][j], 0, 0, 0);
        }
        __builtin_amdgcn_s_barrier();   // all waves done reading buf p before restage
    }

    // epilogue: pack row-pairs (rows 2r, 2r+1) as 2xbf16 in one uint; stream (no atomics).
    // C/D map: col=lane&15, row=(lane>>4)*4+reg -> row0 even, rg pairs {0,1},{2,3}.
    unsigned* pout = parts + (size_t)ksp * (BATCH / 2) * OUT_F;
    const int col  = bn0 + wc * 64 + lr;
    const int row0 = bm0 + wr * 128 + lg * 4;
#pragma unroll
    for (int i = 0; i < 8; ++i) {
        const int rp = (row0 + i * 16) >> 1;    // row-pair index
#pragma unroll
        for (int j = 0; j < 4; ++j) {
            unsigned u0 = bf16_bits(acc[i][j][0]) | (bf16_bits(acc[i][j][1]) << 16);
            unsigned u1 = bf16_bits(acc[i][j][2]) | (bf16_bits(acc[i][j][3]) << 16);
            pout[(size_t)rp * OUT_F + col + j * 16]       = u0;
            pout[(size_t)(rp + 1) * OUT_F + col + j * 16] = u1;
        }
    }
#undef STAGE
}

// ---------------- 3) reduce bf16-packed partials + bias -> out (R14/R20-byte-exact) ----------------
__global__ void reduce_bias_kernel(const unsigned* __restrict__ parts,
                                   const float* __restrict__ bias,
                                   float* __restrict__ out) {
    const int NPQ = (BATCH / 2) * (OUT_F / 4);        // uint4 elements per slice
    int i = blockIdx.x * blockDim.x + threadIdx.x;
    if (i >= NPQ) return;
    float se[4] = {0.f, 0.f, 0.f, 0.f};               // even row (2rp)
    float so[4] = {0.f, 0.f, 0.f, 0.f};               // odd row (2rp+1)
#pragma unroll
    for (int k = 0; k < KSPLIT; ++k) {
        uint4 v = ((const uint4*)parts)[(size_t)k * NPQ + i];
        se[0] += bf16_val(v.x & 0xFFFFu); so[0] += bf16_val(v.x >> 16);
        se[1] += bf16_val(v.y & 0xFFFFu); so[1] += bf16_val(v.y >> 16);
        se[2] += bf16_val(v.z & 0xFFFFu); so[2] += bf16_val(v.z >> 16);
        se[3] += bf16_val(v.w & 0xFFFFu); so[3] += bf16_val(v.w >> 16);
    }
    const int cq = i & (OUT_F / 4 - 1);               // col/4
    const int rp = i / (OUT_F / 4);                   // row pair
    float4 bv = ((const float4*)bias)[cq];
    float4 oe = make_float4(se[0] + bv.x, se[1] + bv.y, se[2] + bv.z, se[3] + bv.w);
    float4 oo = make_float4(so[0] + bv.x, so[1] + bv.y, so[2] + bv.z, so[3] + bv.w);
    ((float4*)out)[(size_t)(2 * rp) * (OUT_F / 4) + cq]     = oe;
    ((float4*)out)[(size_t)(2 * rp + 1) * (OUT_F / 4) + cq] = oo;
}

extern "C" void kernel_launch(void* const* d_in, const int* in_sizes, int n_in,
                              void* d_out, int out_size, void* d_ws, size_t ws_size,
                              hipStream_t stream) {
    const float* x    = (const float*)d_in[0];   // (512, 4096) f32
    const float* wv   = (const float*)d_in[1];   // (nnz,) f32
    const float* bias = (const float*)d_in[2];   // (4096,) f32
    const int*   idx  = (const int*)d_in[3];     // (2, nnz) int32: rows then cols
    const int nnz = in_sizes[1];
    const int* rows = idx;
    const int* cols = idx + nnz;
    float* out = (float*)d_out;

    // workspace layout (16 B aligned chunks)
    char* ws = (char*)d_ws;
    __hip_bfloat16* Wb = (__hip_bfloat16*)ws; ws += (size_t)OUT_F * IN_F * sizeof(__hip_bfloat16); // 32 MB
    __hip_bfloat16* xb = (__hip_bfloat16*)ws; ws += (size_t)BATCH * IN_F * sizeof(__hip_bfloat16); // 4 MB
    unsigned* parts = (unsigned*)ws;          // KSPLIT * (BATCH/2) * OUT_F * 4 B = 32 MB

    // 0) W <- 0 via DMA fill (graph-safe async memset)
    hipMemsetAsync((void*)Wb, 0, (size_t)OUT_F * IN_F * sizeof(__hip_bfloat16), stream);

    // 1) fused: scatter entries into dense bf16 W (CAS add) + x -> bf16
    const int NS = (nnz + 3) / 4;
    const int NTOT = NS + NC4;
    scatter_convert_kernel<<<(NTOT + 255) / 256, 256, 0, stream>>>(
        rows, cols, wv, nnz, (unsigned*)Wb, x, xb);

    // 2) dense MFMA GEMM, 256^2 tile, K-split=8, bf16 partial streams (R20-exact)
    gemm_part_kernel<<<NWG, 512, 0, stream>>>(xb, Wb, parts);

    // 3) sum partials + bias -> out (R20-exact)
    const int NPQ = (BATCH / 2) * (OUT_F / 4);
    reduce_bias_kernel<<<(NPQ + 255) / 256, 256, 0, stream>>>(parts, bias, out);
}

// Round 22
// 66.588 us; speedup vs baseline: 1.0052x; 1.0052x over previous
//
#include <hip/hip_runtime.h>
#include <hip/hip_bf16.h>

#define BATCH  512
#define IN_F   4096
#define OUT_F  4096

typedef __attribute__((ext_vector_type(8))) short bf16x8;   // 8 bf16 = 4 VGPR (MFMA A/B frag)
typedef __attribute__((ext_vector_type(4))) float f32x4;    // MFMA C/D frag

// bf16 round-to-nearest-even bits from fp32
__device__ __forceinline__ unsigned bf16_bits(float f) {
    unsigned u = __float_as_uint(f);
    return (u + 0x7FFFu + ((u >> 16) & 1u)) >> 16;
}
__device__ __forceinline__ float bf16_val(unsigned bits16) {
    return __uint_as_float(bits16 << 16);
}

// ---------------- 0) convert x fp32 -> bf16  +  zero dense W ----------------
__global__ void convert_zero_kernel(const float* __restrict__ x, __hip_bfloat16* __restrict__ xb,
                                    float4* __restrict__ wz) {
    const int NC = BATCH * IN_F / 4;          // 524288 x-convert units (float4 each)
    const int NW = OUT_F * IN_F * 2 / 16;     // 2097152 float4 zero-stores (32 MB)
    int i = blockIdx.x * blockDim.x + threadIdx.x;
    if (i < NC) {
        float4 v = ((const float4*)x)[i];
        unsigned lo = bf16_bits(v.x) | (bf16_bits(v.y) << 16);
        unsigned hi = bf16_bits(v.z) | (bf16_bits(v.w) << 16);
        ((uint2*)xb)[i] = make_uint2(lo, hi);
    } else if (i < NC + NW) {
        wz[i - NC] = make_float4(0.f, 0.f, 0.f, 0.f);
    }
}

// ---------------- 1) scatter: bf16 atomic-add (CAS) directly into dense W ----------------
// Duplicate coords (~1.5% of entries) sum via the CAS loop; contention ~0 so the loop
// runs once almost always. Device-scope CAS -> coherent across XCDs.
__device__ __forceinline__ void add_bf16(unsigned* __restrict__ Wb32, int r, int c, float val) {
    unsigned* addr = &Wb32[((size_t)r * IN_F + c) >> 1];
    const bool hi = c & 1;
    unsigned old = *addr, assumed;
    do {
        assumed = old;
        unsigned cur = hi ? (assumed >> 16) : (assumed & 0xFFFFu);
        unsigned nb  = bf16_bits(bf16_val(cur) + val);
        unsigned next = hi ? ((nb << 16) | (assumed & 0xFFFFu))
                           : ((assumed & 0xFFFF0000u) | nb);
        old = atomicCAS(addr, assumed, next);
    } while (old != assumed);
}

__global__ void scatter_cas_kernel(const int* __restrict__ rows,
                                   const int* __restrict__ cols,
                                   const float* __restrict__ w,
                                   int nnz,
                                   unsigned* __restrict__ Wb32) {
    int i = blockIdx.x * blockDim.x + threadIdx.x;
    int i4 = i * 4;
    if (i4 + 4 <= nnz) {
        int4   r  = ((const int4*)rows)[i];
        int4   c  = ((const int4*)cols)[i];
        float4 wv = ((const float4*)w)[i];
        add_bf16(Wb32, r.x, c.x, wv.x);
        add_bf16(Wb32, r.y, c.y, wv.y);
        add_bf16(Wb32, r.z, c.z, wv.z);
        add_bf16(Wb32, r.w, c.w, wv.w);
    } else {
        for (int j = i4; j < nnz; ++j)
            add_bf16(Wb32, rows[j], cols[j], w[j]);
    }
}

// ---------------- 2) GEMM: part[ksp] = x_bf16 @ W^T (slice) ----------------
// 256^2 tile, BK=64, 8 waves 2Mx4N, counted vmcnt(8), pre-swizzled row-major LDS
// (coalesced staging + 0 bank conflicts, measured). XCD-paired mapping; bf16-packed
// partial streams (no atomics).
#define BM  256
#define BN  256
#define BKT 64
#define KSPLIT 8
#define KH   (IN_F / KSPLIT)            // 512
#define NKTH (KH / BKT)                 // 8
#define NWG  ((BATCH / BM) * (OUT_F / BN) * KSPLIT)   // 256

__global__ __launch_bounds__(512, 1) void gemm_part_kernel(
    const __hip_bfloat16* __restrict__ xb,   // (512, 4096) row-major
    const __hip_bfloat16* __restrict__ Wb,   // (4096, 4096) = (N, K) row-major
    unsigned* __restrict__ parts) {          // KSPLIT x (256, 4096) uint (2 bf16 rows each)

    __shared__ __align__(16) __hip_bfloat16 As[2][BM][BKT];   // 64 KB
    __shared__ __align__(16) __hip_bfloat16 Bs[2][BN][BKT];   // 64 KB

    // XCD-paired decomposition (xcd heuristic: bid % 8)
    const int xcd = blockIdx.x & 7;
    const int r   = blockIdx.x >> 3;          // 0..31
    const int bn0 = (2 * xcd + (r & 1)) * BN; // n tile 0..15
    const int bm0 = ((r >> 1) & 1) * BM;      // m tile 0..1
    const int ksp = r >> 2;                   // 0..7
    const size_t k0 = (size_t)ksp * KH;

    const int t  = threadIdx.x;               // 0..511
    const int l  = t & 63;
    const int w  = t >> 6;                    // wave 0..7
    const int wr = w >> 2;                    // M-half 0..1 (128 rows)
    const int wc = w & 3;                     // N-quarter 0..3 (64 cols)
    const int lr = l & 15;                    // frag lane
    const int lg = l >> 4;                    // k-group 0..3

    f32x4 acc[8][4] = {};

#define STAGE(p, kt) do {                                                                         \
    _Pragma("unroll")                                                                             \
    for (int j = 0; j < 4; ++j) {                                                                 \
        int q = t + j * 512; int row = q >> 3; int kcg = (q & 7) ^ (row & 7);                     \
        __builtin_amdgcn_global_load_lds(                                                         \
            (const unsigned*)(xb + (size_t)(bm0 + row) * IN_F + k0 + (kt) * BKT + kcg * 8),       \
            (unsigned*)((__hip_bfloat16*)As[p] + q * 8), 16, 0, 0);                               \
    }                                                                                             \
    _Pragma("unroll")                                                                             \
    for (int j = 0; j < 4; ++j) {                                                                 \
        int q = t + j * 512; int row = q >> 3; int kcg = (q & 7) ^ (row & 7);                     \
        __builtin_amdgcn_global_load_lds(                                                         \
            (const unsigned*)(Wb + (size_t)(bn0 + row) * IN_F + k0 + (kt) * BKT + kcg * 8),       \
            (unsigned*)((__hip_bfloat16*)Bs[p] + q * 8), 16, 0, 0);                               \
    }                                                                                             \
} while (0)

    const int rowA0 = wr * 128 + lr;          // +16i ; (row&7) == (lr&7) for all i
    const int rowB0 = wc * 64 + lr;
    const int xA = lr & 7;
    const int xB = lr & 7;

    STAGE(0, 0);
    for (int kt = 0; kt < NKTH; ++kt) {
        const int p = kt & 1;
        if (kt + 1 < NKTH) {
            STAGE(p ^ 1, kt + 1);                              // 8 more loads in flight
            asm volatile("s_waitcnt vmcnt(8)" ::: "memory");   // tile kt's 8 landed
        } else {
            asm volatile("s_waitcnt vmcnt(0)" ::: "memory");   // final tile: full drain
        }
        __builtin_amdgcn_s_barrier();                          // all waves: tile kt ready

#pragma unroll
        for (int ks = 0; ks < 2; ++ks) {
            const int kc = ks * 4 + lg;
            bf16x8 a[8], b[4];
#pragma unroll
            for (int i = 0; i < 8; ++i)
                a[i] = *(const bf16x8*)&As[p][rowA0 + 16 * i][(kc ^ xA) * 8];
#pragma unroll
            for (int i = 0; i < 4; ++i)
                b[i] = *(const bf16x8*)&Bs[p][rowB0 + 16 * i][(kc ^ xB) * 8];
#pragma unroll
            for (int i = 0; i < 8; ++i)
#pragma unroll
                for (int j = 0; j < 4; ++j)
                    acc[i][j] = __builtin_amdgcn_mfma_f32_16x16x32_bf16(a[i], b[j], acc[i][j], 0, 0, 0);
        }
        __builtin_amdgcn_s_barrier();   // all waves done reading buf p before restage
    }

    // epilogue: pack row-pairs (rows 2r, 2r+1) as 2xbf16 in one uint; stream (no atomics).
    // C/D map: col=lane&15, row=(lane>>4)*4+reg -> row0 even, rg pairs {0,1},{2,3}.
    unsigned* pout = parts + (size_t)ksp * (BATCH / 2) * OUT_F;
    const int col  = bn0 + wc * 64 + lr;
    const int row0 = bm0 + wr * 128 + lg * 4;
#pragma unroll
    for (int i = 0; i < 8; ++i) {
        const int rp = (row0 + i * 16) >> 1;    // row-pair index
#pragma unroll
        for (int j = 0; j < 4; ++j) {
            unsigned u0 = bf16_bits(acc[i][j][0]) | (bf16_bits(acc[i][j][1]) << 16);
            unsigned u1 = bf16_bits(acc[i][j][2]) | (bf16_bits(acc[i][j][3]) << 16);
            pout[(size_t)rp * OUT_F + col + j * 16]       = u0;
            pout[(size_t)(rp + 1) * OUT_F + col + j * 16] = u1;
        }
    }
#undef STAGE
}

// ---------------- 3) reduce bf16-packed partials + bias -> out ----------------
__global__ void reduce_bias_kernel(const unsigned* __restrict__ parts,
                                   const float* __restrict__ bias,
                                   float* __restrict__ out) {
    const int NPQ = (BATCH / 2) * (OUT_F / 4);        // uint4 elements per slice
    int i = blockIdx.x * blockDim.x + threadIdx.x;
    if (i >= NPQ) return;
    float se[4] = {0.f, 0.f, 0.f, 0.f};               // even row (2rp)
    float so[4] = {0.f, 0.f, 0.f, 0.f};               // odd row (2rp+1)
#pragma unroll
    for (int k = 0; k < KSPLIT; ++k) {
        uint4 v = ((const uint4*)parts)[(size_t)k * NPQ + i];
        se[0] += bf16_val(v.x & 0xFFFFu); so[0] += bf16_val(v.x >> 16);
        se[1] += bf16_val(v.y & 0xFFFFu); so[1] += bf16_val(v.y >> 16);
        se[2] += bf16_val(v.z & 0xFFFFu); so[2] += bf16_val(v.z >> 16);
        se[3] += bf16_val(v.w & 0xFFFFu); so[3] += bf16_val(v.w >> 16);
    }
    const int cq = i & (OUT_F / 4 - 1);               // col/4
    const int rp = i / (OUT_F / 4);                   // row pair
    float4 bv = ((const float4*)bias)[cq];
    float4 oe = make_float4(se[0] + bv.x, se[1] + bv.y, se[2] + bv.z, se[3] + bv.w);
    float4 oo = make_float4(so[0] + bv.x, so[1] + bv.y, so[2] + bv.z, so[3] + bv.w);
    ((float4*)out)[(size_t)(2 * rp) * (OUT_F / 4) + cq]     = oe;
    ((float4*)out)[(size_t)(2 * rp + 1) * (OUT_F / 4) + cq] = oo;
}

extern "C" void kernel_launch(void* const* d_in, const int* in_sizes, int n_in,
                              void* d_out, int out_size, void* d_ws, size_t ws_size,
                              hipStream_t stream) {
    const float* x    = (const float*)d_in[0];   // (512, 4096) f32
    const float* wv   = (const float*)d_in[1];   // (nnz,) f32
    const float* bias = (const float*)d_in[2];   // (4096,) f32
    const int*   idx  = (const int*)d_in[3];     // (2, nnz) int32: rows then cols
    const int nnz = in_sizes[1];
    const int* rows = idx;
    const int* cols = idx + nnz;
    float* out = (float*)d_out;

    // workspace layout (16 B aligned chunks)
    char* ws = (char*)d_ws;
    __hip_bfloat16* Wb = (__hip_bfloat16*)ws; ws += (size_t)OUT_F * IN_F * sizeof(__hip_bfloat16); // 32 MB
    __hip_bfloat16* xb = (__hip_bfloat16*)ws; ws += (size_t)BATCH * IN_F * sizeof(__hip_bfloat16); // 4 MB
    unsigned* parts = (unsigned*)ws;          // KSPLIT * (BATCH/2) * OUT_F * 4 B = 32 MB

    // 0) x->bf16 + Wb<-0 (fused streaming pass; in-kernel zero beats hipMemsetAsync)
    const int NTOT = BATCH * IN_F / 4 + OUT_F * IN_F * 2 / 16;
    convert_zero_kernel<<<(NTOT + 255) / 256, 256, 0, stream>>>(x, xb, (float4*)Wb);

    // 1) scatter entries directly into dense bf16 W (CAS add; duplicates summed)
    int nthreads = (nnz + 3) / 4;
    int nb = (nthreads + 255) / 256;
    scatter_cas_kernel<<<nb, 256, 0, stream>>>(rows, cols, wv, nnz, (unsigned*)Wb);

    // 2) dense MFMA GEMM, 256^2 tile, K-split=8, bf16 partial streams
    gemm_part_kernel<<<NWG, 512, 0, stream>>>(xb, Wb, parts);

    // 3) sum partials + bias -> out
    const int NPQ = (BATCH / 2) * (OUT_F / 4);
    reduce_bias_kernel<<<(NPQ + 255) / 256, 256, 0, stream>>>(parts, bias, out);
}

// Round 23
// 66.327 us; speedup vs baseline: 1.0091x; 1.0039x over previous
//
#include <hip/hip_runtime.h>
#include <hip/hip_bf16.h>

#define BATCH  512
#define IN_F   4096
#define OUT_F  4096

typedef __attribute__((ext_vector_type(8))) short bf16x8;   // 8 bf16 = 4 VGPR (MFMA A/B frag)
typedef __attribute__((ext_vector_type(4))) float f32x4;    // MFMA C/D frag

// bf16 round-to-nearest-even bits from fp32
__device__ __forceinline__ unsigned bf16_bits(float f) {
    unsigned u = __float_as_uint(f);
    return (u + 0x7FFFu + ((u >> 16) & 1u)) >> 16;
}
__device__ __forceinline__ float bf16_val(unsigned bits16) {
    return __uint_as_float(bits16 << 16);
}

// ---------------- 0) convert x fp32 -> bf16  +  zero dense W ----------------
__global__ void convert_zero_kernel(const float* __restrict__ x, __hip_bfloat16* __restrict__ xb,
                                    float4* __restrict__ wz) {
    const int NC = BATCH * IN_F / 4;          // 524288 x-convert units (float4 each)
    const int NW = OUT_F * IN_F * 2 / 16;     // 2097152 float4 zero-stores (32 MB)
    int i = blockIdx.x * blockDim.x + threadIdx.x;
    if (i < NC) {
        float4 v = ((const float4*)x)[i];
        unsigned lo = bf16_bits(v.x) | (bf16_bits(v.y) << 16);
        unsigned hi = bf16_bits(v.z) | (bf16_bits(v.w) << 16);
        ((uint2*)xb)[i] = make_uint2(lo, hi);
    } else if (i < NC + NW) {
        wz[i - NC] = make_float4(0.f, 0.f, 0.f, 0.f);
    }
}

// ---------------- 1) scatter: bf16 atomic-add (CAS) directly into dense W ----------------
// Duplicate coords (~1.5% of entries) sum via the CAS loop; contention ~0 so the loop
// runs once almost always. Device-scope CAS -> coherent across XCDs.
__device__ __forceinline__ void add_bf16(unsigned* __restrict__ Wb32, int r, int c, float val) {
    unsigned* addr = &Wb32[((size_t)r * IN_F + c) >> 1];
    const bool hi = c & 1;
    unsigned old = *addr, assumed;
    do {
        assumed = old;
        unsigned cur = hi ? (assumed >> 16) : (assumed & 0xFFFFu);
        unsigned nb  = bf16_bits(bf16_val(cur) + val);
        unsigned next = hi ? ((nb << 16) | (assumed & 0xFFFFu))
                           : ((assumed & 0xFFFF0000u) | nb);
        old = atomicCAS(addr, assumed, next);
    } while (old != assumed);
}

__global__ void scatter_cas_kernel(const int* __restrict__ rows,
                                   const int* __restrict__ cols,
                                   const float* __restrict__ w,
                                   int nnz,
                                   unsigned* __restrict__ Wb32) {
    int i = blockIdx.x * blockDim.x + threadIdx.x;
    int i4 = i * 4;
    if (i4 + 4 <= nnz) {
        int4   r  = ((const int4*)rows)[i];
        int4   c  = ((const int4*)cols)[i];
        float4 wv = ((const float4*)w)[i];
        add_bf16(Wb32, r.x, c.x, wv.x);
        add_bf16(Wb32, r.y, c.y, wv.y);
        add_bf16(Wb32, r.z, c.z, wv.z);
        add_bf16(Wb32, r.w, c.w, wv.w);
    } else {
        for (int j = i4; j < nnz; ++j)
            add_bf16(Wb32, rows[j], cols[j], w[j]);
    }
}

// ---------------- 2) GEMM: part[ksp] = x_bf16 @ W^T (slice) ----------------
// 256^2 tile, BK=64, 8 waves 2Mx4N, counted vmcnt(8), pre-swizzled row-major LDS
// (coalesced staging + 0 bank conflicts, measured). XCD-paired mapping; bf16-packed
// partial streams (no atomics).
#define BM  256
#define BN  256
#define BKT 64
#define KSPLIT 8
#define KH   (IN_F / KSPLIT)            // 512
#define NKTH (KH / BKT)                 // 8
#define NWG  ((BATCH / BM) * (OUT_F / BN) * KSPLIT)   // 256

__global__ __launch_bounds__(512, 1) void gemm_part_kernel(
    const __hip_bfloat16* __restrict__ xb,   // (512, 4096) row-major
    const __hip_bfloat16* __restrict__ Wb,   // (4096, 4096) = (N, K) row-major
    unsigned* __restrict__ parts) {          // KSPLIT x (256, 4096) uint (2 bf16 rows each)

    __shared__ __align__(16) __hip_bfloat16 As[2][BM][BKT];   // 64 KB
    __shared__ __align__(16) __hip_bfloat16 Bs[2][BN][BKT];   // 64 KB

    // XCD-paired decomposition (xcd heuristic: bid % 8)
    const int xcd = blockIdx.x & 7;
    const int r   = blockIdx.x >> 3;          // 0..31
    const int bn0 = (2 * xcd + (r & 1)) * BN; // n tile 0..15
    const int bm0 = ((r >> 1) & 1) * BM;      // m tile 0..1
    const int ksp = r >> 2;                   // 0..7
    const size_t k0 = (size_t)ksp * KH;

    const int t  = threadIdx.x;               // 0..511
    const int l  = t & 63;
    const int w  = t >> 6;                    // wave 0..7
    const int wr = w >> 2;                    // M-half 0..1 (128 rows)
    const int wc = w & 3;                     // N-quarter 0..3 (64 cols)
    const int lr = l & 15;                    // frag lane
    const int lg = l >> 4;                    // k-group 0..3

    f32x4 acc[8][4] = {};

#define STAGE(p, kt) do {                                                                         \
    _Pragma("unroll")                                                                             \
    for (int j = 0; j < 4; ++j) {                                                                 \
        int q = t + j * 512; int row = q >> 3; int kcg = (q & 7) ^ (row & 7);                     \
        __builtin_amdgcn_global_load_lds(                                                         \
            (const unsigned*)(xb + (size_t)(bm0 + row) * IN_F + k0 + (kt) * BKT + kcg * 8),       \
            (unsigned*)((__hip_bfloat16*)As[p] + q * 8), 16, 0, 0);                               \
    }                                                                                             \
    _Pragma("unroll")                                                                             \
    for (int j = 0; j < 4; ++j) {                                                                 \
        int q = t + j * 512; int row = q >> 3; int kcg = (q & 7) ^ (row & 7);                     \
        __builtin_amdgcn_global_load_lds(                                                         \
            (const unsigned*)(Wb + (size_t)(bn0 + row) * IN_F + k0 + (kt) * BKT + kcg * 8),       \
            (unsigned*)((__hip_bfloat16*)Bs[p] + q * 8), 16, 0, 0);                               \
    }                                                                                             \
} while (0)

    const int rowA0 = wr * 128 + lr;          // +16i ; (row&7) == (lr&7) for all i
    const int rowB0 = wc * 64 + lr;
    const int xA = lr & 7;
    const int xB = lr & 7;

    STAGE(0, 0);
    for (int kt = 0; kt < NKTH; ++kt) {
        const int p = kt & 1;
        if (kt + 1 < NKTH) {
            STAGE(p ^ 1, kt + 1);                              // 8 more loads in flight
            asm volatile("s_waitcnt vmcnt(8)" ::: "memory");   // tile kt's 8 landed
        } else {
            asm volatile("s_waitcnt vmcnt(0)" ::: "memory");   // final tile: full drain
        }
        __builtin_amdgcn_s_barrier();                          // all waves: tile kt ready

#pragma unroll
        for (int ks = 0; ks < 2; ++ks) {
            const int kc = ks * 4 + lg;
            bf16x8 a[8], b[4];
#pragma unroll
            for (int i = 0; i < 8; ++i)
                a[i] = *(const bf16x8*)&As[p][rowA0 + 16 * i][(kc ^ xA) * 8];
#pragma unroll
            for (int i = 0; i < 4; ++i)
                b[i] = *(const bf16x8*)&Bs[p][rowB0 + 16 * i][(kc ^ xB) * 8];
#pragma unroll
            for (int i = 0; i < 8; ++i)
#pragma unroll
                for (int j = 0; j < 4; ++j)
                    acc[i][j] = __builtin_amdgcn_mfma_f32_16x16x32_bf16(a[i], b[j], acc[i][j], 0, 0, 0);
        }
        __builtin_amdgcn_s_barrier();   // all waves done reading buf p before restage
    }

    // epilogue: pack row-pairs (rows 2r, 2r+1) as 2xbf16 in one uint; stream (no atomics).
    // C/D map: col=lane&15, row=(lane>>4)*4+reg -> row0 even, rg pairs {0,1},{2,3}.
    unsigned* pout = parts + (size_t)ksp * (BATCH / 2) * OUT_F;
    const int col  = bn0 + wc * 64 + lr;
    const int row0 = bm0 + wr * 128 + lg * 4;
#pragma unroll
    for (int i = 0; i < 8; ++i) {
        const int rp = (row0 + i * 16) >> 1;    // row-pair index
#pragma unroll
        for (int j = 0; j < 4; ++j) {
            unsigned u0 = bf16_bits(acc[i][j][0]) | (bf16_bits(acc[i][j][1]) << 16);
            unsigned u1 = bf16_bits(acc[i][j][2]) | (bf16_bits(acc[i][j][3]) << 16);
            pout[(size_t)rp * OUT_F + col + j * 16]       = u0;
            pout[(size_t)(rp + 1) * OUT_F + col + j * 16] = u1;
        }
    }
#undef STAGE
}

// ---------------- 3) reduce bf16-packed partials + bias -> out ----------------
__global__ void reduce_bias_kernel(const unsigned* __restrict__ parts,
                                   const float* __restrict__ bias,
                                   float* __restrict__ out) {
    const int NPQ = (BATCH / 2) * (OUT_F / 4);        // uint4 elements per slice
    int i = blockIdx.x * blockDim.x + threadIdx.x;
    if (i >= NPQ) return;
    float se[4] = {0.f, 0.f, 0.f, 0.f};               // even row (2rp)
    float so[4] = {0.f, 0.f, 0.f, 0.f};               // odd row (2rp+1)
#pragma unroll
    for (int k = 0; k < KSPLIT; ++k) {
        uint4 v = ((const uint4*)parts)[(size_t)k * NPQ + i];
        se[0] += bf16_val(v.x & 0xFFFFu); so[0] += bf16_val(v.x >> 16);
        se[1] += bf16_val(v.y & 0xFFFFu); so[1] += bf16_val(v.y >> 16);
        se[2] += bf16_val(v.z & 0xFFFFu); so[2] += bf16_val(v.z >> 16);
        se[3] += bf16_val(v.w & 0xFFFFu); so[3] += bf16_val(v.w >> 16);
    }
    const int cq = i & (OUT_F / 4 - 1);               // col/4
    const int rp = i / (OUT_F / 4);                   // row pair
    float4 bv = ((const float4*)bias)[cq];
    float4 oe = make_float4(se[0] + bv.x, se[1] + bv.y, se[2] + bv.z, se[3] + bv.w);
    float4 oo = make_float4(so[0] + bv.x, so[1] + bv.y, so[2] + bv.z, so[3] + bv.w);
    ((float4*)out)[(size_t)(2 * rp) * (OUT_F / 4) + cq]     = oe;
    ((float4*)out)[(size_t)(2 * rp + 1) * (OUT_F / 4) + cq] = oo;
}

extern "C" void kernel_launch(void* const* d_in, const int* in_sizes, int n_in,
                              void* d_out, int out_size, void* d_ws, size_t ws_size,
                              hipStream_t stream) {
    const float* x    = (const float*)d_in[0];   // (512, 4096) f32
    const float* wv   = (const float*)d_in[1];   // (nnz,) f32
    const float* bias = (const float*)d_in[2];   // (4096,) f32
    const int*   idx  = (const int*)d_in[3];     // (2, nnz) int32: rows then cols
    const int nnz = in_sizes[1];
    const int* rows = idx;
    const int* cols = idx + nnz;
    float* out = (float*)d_out;

    // workspace layout (16 B aligned chunks)
    char* ws = (char*)d_ws;
    __hip_bfloat16* Wb = (__hip_bfloat16*)ws; ws += (size_t)OUT_F * IN_F * sizeof(__hip_bfloat16); // 32 MB
    __hip_bfloat16* xb = (__hip_bfloat16*)ws; ws += (size_t)BATCH * IN_F * sizeof(__hip_bfloat16); // 4 MB
    unsigned* parts = (unsigned*)ws;          // KSPLIT * (BATCH/2) * OUT_F * 4 B = 32 MB

    // 0) x->bf16 + Wb<-0 (fused streaming pass; in-kernel zero beats hipMemsetAsync)
    const int NTOT = BATCH * IN_F / 4 + OUT_F * IN_F * 2 / 16;
    convert_zero_kernel<<<(NTOT + 255) / 256, 256, 0, stream>>>(x, xb, (float4*)Wb);

    // 1) scatter entries directly into dense bf16 W (CAS add; duplicates summed)
    int nthreads = (nnz + 3) / 4;
    int nb = (nthreads + 255) / 256;
    scatter_cas_kernel<<<nb, 256, 0, stream>>>(rows, cols, wv, nnz, (unsigned*)Wb);

    // 2) dense MFMA GEMM, 256^2 tile, K-split=8, bf16 partial streams
    gemm_part_kernel<<<NWG, 512, 0, stream>>>(xb, Wb, parts);

    // 3) sum partials + bias -> out
    const int NPQ = (BATCH / 2) * (OUT_F / 4);
    reduce_bias_kernel<<<(NPQ + 255) / 256, 256, 0, stream>>>(parts, bias, out);
}